// Round 1
// 748.079 us; speedup vs baseline: 2.0452x; 2.0452x over previous
//
#include <hip/hip_runtime.h>
#include <hip/hip_bf16.h>
#include <stdint.h>

// RNN-T prediction network: embed lookup + 2-layer LSTM, U=128, N=512, C=320.
// FP32 in/out; internal GEMMs bf16 MFMA + fp32 accumulate.
// Persistent cooperative kernel, 256 WGs = 16 batch-groups x 16 hidden-groups.
// R5: fence-free inter-WG exchange. The old barrier used RELEASE(agent) flag
//     store + __threadfence(): on gfx950 those compile to buffer_wbl2 (flush
//     dirty L2 -> IC/HBM) + buffer_inv (invalidate L1/L2) EVERY tick in EVERY
//     WG. Evidence: WRITE_SIZE 196MB = out(89MB) + ALL Hx exchange traffic
//     (84MB) forced to HBM. New protocol: Hx data + flags move via RELAXED
//     AGENT-scope atomics (coherent at Infinity Cache, bypass L1/L2); ordering
//     = vmcnt(0) drain + workgroup barrier + per-wave in-order vmem issue.
//     Correct for any WG->XCD mapping; zero cache-maintenance ops in the loop.
//     Also: v_rcp instead of full-precision divides in sigm/tanh.

typedef short short8 __attribute__((ext_vector_type(8)));
typedef float f32x4 __attribute__((ext_vector_type(4)));

#define USTEPS 128
#define HSZ    (512*320)
#define GSTEP  (512*320)
#define HGOFF  (128*512*320)
#define CGOFF  (HGOFF + 2*512*320)
#define FLAGSTRIDE 16   // uint32s = 64B per slot

__device__ __forceinline__ uint16_t f2bf(float f) {
  union { float f; uint32_t i; } v; v.f = f;
  uint32_t i = v.i;
  return (uint16_t)((i + 0x7fffu + ((i >> 16) & 1u)) >> 16);
}
__device__ __forceinline__ float rcp_(float x) { return __builtin_amdgcn_rcpf(x); }
__device__ __forceinline__ float sigm(float x) { return rcp_(1.0f + __expf(-x)); }
__device__ __forceinline__ float tanh_(float x) {
  float ax = fabsf(x);
  float e  = __expf(-2.0f * ax);
  float t  = (1.0f - e) * rcp_(1.0f + e);
  return x < 0.0f ? -t : t;
}
__device__ __forceinline__ uint4 cvt8(const float* s) {
  float4 a = ((const float4*)s)[0];
  float4 b = ((const float4*)s)[1];
  uint4 r;
  r.x = (uint32_t)f2bf(a.x) | ((uint32_t)f2bf(a.y) << 16);
  r.y = (uint32_t)f2bf(a.z) | ((uint32_t)f2bf(a.w) << 16);
  r.z = (uint32_t)f2bf(b.x) | ((uint32_t)f2bf(b.y) << 16);
  r.w = (uint32_t)f2bf(b.z) | ((uint32_t)f2bf(b.w) << 16);
  return r;
}
__device__ __forceinline__ short8 loadw8(const float* p) {
  float4 a = ((const float4*)p)[0];
  float4 b = ((const float4*)p)[1];
  short8 r;
  r[0] = (short)f2bf(a.x); r[1] = (short)f2bf(a.y);
  r[2] = (short)f2bf(a.z); r[3] = (short)f2bf(a.w);
  r[4] = (short)f2bf(b.x); r[5] = (short)f2bf(b.y);
  r[6] = (short)f2bf(b.z); r[7] = (short)f2bf(b.w);
  return r;
}

// ---------------------------------------------------------------------------
// prep: G0p table, bias1p, flag zeroing, AND h0 -> bf16 prefill of exchange
// slots: Hx0[slot1] <- bf16(h0 layer0), Hx1[slot1] <- bf16(h0 layer1).
// (Normal stores are fine here: kernel-end release writes back L2, so the
//  main kernel's IC-coherent atomic loads see them.)
// ---------------------------------------------------------------------------
#define PREP_G0   (29 * 1280)
#define PREP_B1   (PREP_G0 + 1280)
#define PREP_FL   (PREP_B1 + 4096)
#define PREP_HI   (PREP_FL + 2 * 512 * 40)   // 40960 cvt8 items
__global__ void prep_kernel(const float* __restrict__ embed,
                            const float* __restrict__ w_ih,
                            const float* __restrict__ b_ih,
                            const float* __restrict__ b_hh,
                            const float* __restrict__ h0,
                            float* __restrict__ G0p,
                            float* __restrict__ bias1p,
                            uint32_t* __restrict__ flags,
                            uint16_t* __restrict__ Hx0,
                            uint16_t* __restrict__ Hx1) {
  int tid = blockIdx.x * blockDim.x + threadIdx.x;
  if (tid < PREP_G0) {
    int v = tid / 1280, col = tid % 1280;
    int hg = col / 80, idx = col % 80;
    int k = idx >> 2, q = idx & 3;
    int r = q * 320 + hg * 20 + k;
    float acc = b_ih[r] + b_hh[r];
    if (v < 28) {
      const float4* e = (const float4*)(embed + (size_t)v * 320);
      const float4* w = (const float4*)(w_ih + (size_t)r * 320);
#pragma unroll 4
      for (int i = 0; i < 80; ++i) {
        float4 a = e[i], b = w[i];
        acc += a.x * b.x + a.y * b.y + a.z * b.z + a.w * b.w;
      }
    }
    G0p[tid] = acc;
  } else if (tid < PREP_B1) {
    int col = tid - PREP_G0;
    int hg = col / 80, idx = col % 80;
    int k = idx >> 2, q = idx & 3;
    int r = q * 320 + hg * 20 + k;
    bias1p[col] = b_ih[1280 + r] + b_hh[1280 + r];
  } else if (tid < PREP_FL) {
    flags[tid - PREP_B1] = 0;
  } else if (tid < PREP_HI) {
    int id = tid - PREP_FL;              // 0..40959, 8 elements each
    int layer = id / 20480;
    int rem = id - layer * 20480;        // n*40 + c
    int n = rem / 40, c = rem - n * 40;
    const float* src = h0 + (size_t)layer * HSZ + (size_t)n * 320 + c * 8;
    uint16_t* dst = (layer ? Hx1 : Hx0) + HSZ + (size_t)n * 320 + c * 8;
    *(uint4*)dst = cvt8(src);
  }
}

// ---------------------------------------------------------------------------
// main persistent kernel
// ---------------------------------------------------------------------------
__global__ void __launch_bounds__(320, 2)
rnnt_kernel(const int* __restrict__ x,
            const float* __restrict__ c0,
            const float* __restrict__ w_ih,
            const float* __restrict__ w_hh,
            const float* __restrict__ G0p,
            const float* __restrict__ bias1p,
            uint16_t* __restrict__ Hx0,
            uint16_t* __restrict__ Hx1,
            uint32_t* __restrict__ flags,
            float* __restrict__ out) {
  __shared__ __align__(16) uint16_t Hl0[32 * 320];   // h0[t-1] slice (bf16), rot-swizzled
  __shared__ __align__(16) uint16_t Hl1[32 * 320];   // h1[t-2] slice (bf16), rot-swizzled
  __shared__ __align__(16) float    gates0[32 * 84]; // padded stride 84
  __shared__ __align__(16) float    gates1[32 * 84];

  const int tid  = threadIdx.x;
  const int wave = tid >> 6;
  const int lane = tid & 63;
  const int quad = lane >> 4;
  const int lm   = lane & 15;
  const int blk  = blockIdx.x;
  // XCD-swizzle heuristic (performance only; correctness is XCD-agnostic):
  // the 16 WGs of one batch-group share blk%8 -> same XCD
  const int bg = (blk & 7) * 2 + (blk >> 7);         // 0..15 batch-group
  const int hg = (blk >> 3) & 15;                    // 0..15 hidden-group

  // ---- persistent weight fragments (bf16): wave owns 16 gate-cols
  short8 Bhh0[10], Bih1[10], Bhh1[10];
  {
    int ncol = wave * 16 + lm;       // local col 0..79 (= 4k+q)
    int k = ncol >> 2, q = ncol & 3;
    int r = q * 320 + hg * 20 + k;   // original gate row
    const float* p0 = w_hh + (size_t)r * 320 + quad * 8;
    const float* p1 = w_hh + (size_t)(1280 + r) * 320 + quad * 8;
    const float* pi = w_ih + (size_t)(1280 + r) * 320 + quad * 8;
#pragma unroll
    for (int kk = 0; kk < 10; ++kk) {
      Bhh0[kk] = loadw8(p0 + kk * 32);
      Bhh1[kk] = loadw8(p1 + kk * 32);
      Bih1[kk] = loadw8(pi + kk * 32);
    }
  }
  const float bias1v = bias1p[hg * 80 + wave * 16 + lm];

  // ---- pointwise mapping: thread -> (batch row un, hidden pair kc..kc+1)
  const int un  = tid / 10;
  const int ukp = tid - un * 10;
  const int n_g = bg * 32 + un;
  const int kc  = hg * 20 + ukp * 2;

  // ---- staging address precompute (constant across ticks), 8B granularity
  int smc[8], spc[8];
#pragma unroll
  for (int it = 0; it < 8; ++it) {
    int cid = tid + it * 320;        // 0..2559 = 32 rows x 80 chunks(8B)
    int m = cid / 80;
    int c8 = cid - m * 80;
    int c16 = c8 >> 1, h = c8 & 1;
    int p16 = c16 + m; if (p16 >= 40) p16 -= 40;    // same 16B rotation as before
    smc[it] = m * 320 + c8 * 4;                      // global offset (elements)
    spc[it] = m * 320 + p16 * 8 + h * 4;             // LDS offset (elements)
  }
  const size_t gbase = (size_t)bg * 32 * 320;

  float c0s0 = c0[(size_t)n_g * 320 + kc];
  float c0s1 = c0[(size_t)n_g * 320 + kc + 1];
  float c1s0 = c0[(size_t)(512 + n_g) * 320 + kc];
  float c1s1 = c0[(size_t)(512 + n_g) * 320 + kc + 1];

  uint32_t* myflag = flags + (size_t)(bg * 16 + hg) * FLAGSTRIDE;

  // ---- prefetch x/G0p row for tick 0
  float4 gxa, gxb;
  {
    const int v = x[n_g];
    const float* gx = G0p + (size_t)v * 1280 + hg * 80 + ukp * 8;
    gxa = ((const float4*)gx)[0];
    gxb = ((const float4*)gx)[1];
  }

#pragma unroll 1
  for (int t = 0; t <= USTEPS; ++t) {
    const bool do0 = (t < USTEPS);
    const bool do1 = (t >= 1);

    const uint16_t* s0b = Hx0 + (size_t)((t - 1) & 1) * HSZ + gbase;
    const uint16_t* s1b = Hx1 + (size_t)(t & 1) * HSZ + gbase;

    // ---- batched staging: 16 IC-coherent 8B loads in flight, then LDS writes.
    // Agent-relaxed atomic loads bypass L1/L2 -> cannot read stale lines,
    // regardless of which XCD the producer ran on. Issued (in wave program
    // order) strictly after the poll-barrier below, so data is ready in IC.
    unsigned long long r0[8], r1[8];
#pragma unroll
    for (int it = 0; it < 8; ++it)
      r0[it] = __hip_atomic_load((unsigned long long*)(s0b + smc[it]),
                                 __ATOMIC_RELAXED, __HIP_MEMORY_SCOPE_AGENT);
#pragma unroll
    for (int it = 0; it < 8; ++it)
      r1[it] = __hip_atomic_load((unsigned long long*)(s1b + smc[it]),
                                 __ATOMIC_RELAXED, __HIP_MEMORY_SCOPE_AGENT);
#pragma unroll
    for (int it = 0; it < 8; ++it) {
      *(unsigned long long*)(Hl0 + spc[it]) = r0[it];
      *(unsigned long long*)(Hl1 + spc[it]) = r1[it];
    }
    __syncthreads();

    // ---- GEMMs: gates0 = h0prev@Whh0^T ; gates1 = h0prev@Wih1^T + h1prev@Whh1^T (+bias)
    f32x4 ag00 = {0.f, 0.f, 0.f, 0.f}, ag01 = {0.f, 0.f, 0.f, 0.f};
    f32x4 ag10 = {bias1v, bias1v, bias1v, bias1v}, ag11 = ag10;
#pragma unroll
    for (int kk = 0; kk < 10; ++kk) {
      int cch = kk * 4 + quad;
      int p0a = cch + lm;      if (p0a >= 40) p0a -= 40;
      int p1a = cch + lm + 16; if (p1a >= 40) p1a -= 40;
      short8 a00 = *(const short8*)(Hl0 + lm * 320 + p0a * 8);
      short8 a01 = *(const short8*)(Hl0 + (lm + 16) * 320 + p1a * 8);
      if (do0) {
        ag00 = __builtin_amdgcn_mfma_f32_16x16x32_bf16(a00, Bhh0[kk], ag00, 0, 0, 0);
        ag01 = __builtin_amdgcn_mfma_f32_16x16x32_bf16(a01, Bhh0[kk], ag01, 0, 0, 0);
      }
      if (do1) {
        short8 a10 = *(const short8*)(Hl1 + lm * 320 + p0a * 8);
        short8 a11 = *(const short8*)(Hl1 + (lm + 16) * 320 + p1a * 8);
        ag10 = __builtin_amdgcn_mfma_f32_16x16x32_bf16(a00, Bih1[kk], ag10, 0, 0, 0);
        ag11 = __builtin_amdgcn_mfma_f32_16x16x32_bf16(a01, Bih1[kk], ag11, 0, 0, 0);
        ag10 = __builtin_amdgcn_mfma_f32_16x16x32_bf16(a10, Bhh1[kk], ag10, 0, 0, 0);
        ag11 = __builtin_amdgcn_mfma_f32_16x16x32_bf16(a11, Bhh1[kk], ag11, 0, 0, 0);
      }
    }

    // ---- both gate tiles -> LDS, single sync
    if (do0) {
#pragma unroll
      for (int r = 0; r < 4; ++r) {
        gates0[(quad * 4 + r) * 84 + wave * 16 + lm]      = ag00[r];
        gates0[(16 + quad * 4 + r) * 84 + wave * 16 + lm] = ag01[r];
      }
    }
    if (do1) {
#pragma unroll
      for (int r = 0; r < 4; ++r) {
        gates1[(quad * 4 + r) * 84 + wave * 16 + lm]      = ag10[r];
        gates1[(16 + quad * 4 + r) * 84 + wave * 16 + lm] = ag11[r];
      }
    }
    __syncthreads();

    // ---- layer 0 pointwise -> h0 exchange (bf16 Hx0, IC-coherent store)
    if (do0) {
      const float* gp = gates0 + un * 84 + ukp * 8;
      float i0 = gp[0] + gxa.x, f0 = gp[1] + gxa.y, g0 = gp[2] + gxa.z, o0 = gp[3] + gxa.w;
      float i1 = gp[4] + gxb.x, f1 = gp[5] + gxb.y, g1 = gp[6] + gxb.z, o1 = gp[7] + gxb.w;
      c0s0 = sigm(f0) * c0s0 + sigm(i0) * tanh_(g0);
      c0s1 = sigm(f1) * c0s1 + sigm(i1) * tanh_(g1);
      float ha = sigm(o0) * tanh_(c0s0);
      float hb = sigm(o1) * tanh_(c0s1);
      uint32_t packed = (uint32_t)f2bf(ha) | ((uint32_t)f2bf(hb) << 16);
      __hip_atomic_store((uint32_t*)(Hx0 + (size_t)(t & 1) * HSZ + (size_t)n_g * 320 + kc),
                         packed, __ATOMIC_RELAXED, __HIP_MEMORY_SCOPE_AGENT);
      if (t == USTEPS - 1) {
        *(float2*)(out + HGOFF + (size_t)n_g * 320 + kc) = make_float2(ha, hb);
        *(float2*)(out + CGOFF + (size_t)n_g * 320 + kc) = make_float2(c0s0, c0s1);
      }
    }

    // ---- layer 1 pointwise -> fp32 g output + bf16 Hx1 exchange
    if (do1) {
      const int u1 = t - 1;
      const float* gp = gates1 + un * 84 + ukp * 8;
      float i0 = gp[0], f0 = gp[1], g0 = gp[2], o0 = gp[3];
      float i1 = gp[4], f1 = gp[5], g1 = gp[6], o1 = gp[7];
      c1s0 = sigm(f0) * c1s0 + sigm(i0) * tanh_(g0);
      c1s1 = sigm(f1) * c1s1 + sigm(i1) * tanh_(g1);
      float ha = sigm(o0) * tanh_(c1s0);
      float hb = sigm(o1) * tanh_(c1s1);
      *(float2*)(out + (size_t)u1 * GSTEP + (size_t)n_g * 320 + kc) = make_float2(ha, hb);
      uint32_t packed = (uint32_t)f2bf(ha) | ((uint32_t)f2bf(hb) << 16);
      __hip_atomic_store((uint32_t*)(Hx1 + (size_t)((t + 1) & 1) * HSZ + (size_t)n_g * 320 + kc),
                         packed, __ATOMIC_RELAXED, __HIP_MEMORY_SCOPE_AGENT);
      if (t == USTEPS) {
        *(float2*)(out + HGOFF + (size_t)(512 + n_g) * 320 + kc) = make_float2(ha, hb);
        *(float2*)(out + CGOFF + (size_t)(512 + n_g) * 320 + kc) = make_float2(c1s0, c1s1);
      }
    }

    // ---- prefetch next tick's x/G0p row (read-only; overlaps barrier latency)
    if (t + 1 < USTEPS) {
      const int v = x[(t + 1) * 512 + n_g];
      const float* gx = G0p + (size_t)v * 1280 + hg * 80 + ukp * 8;
      gxa = ((const float4*)gx)[0];
      gxb = ((const float4*)gx)[1];
    }

    // ---- fence-free group barrier:
    //  1) per-wave vmcnt(0): all this-WG Hx atomic stores acknowledged at IC
    //  2) __syncthreads: whole WG drained
    //  3) thread 0 publishes flag with a RELAXED agent store (ordering came
    //     from the drain -- no buffer_wbl2, no buffer_inv anywhere)
    //  4) 16 lanes poll peers' flags with relaxed agent loads (IC-coherent)
    if (t < USTEPS) {
      asm volatile("s_waitcnt vmcnt(0)" ::: "memory");
      __syncthreads();
      if (tid < 16) {
        if (tid == 0) {
          __hip_atomic_store(myflag, (uint32_t)(t + 1), __ATOMIC_RELAXED,
                             __HIP_MEMORY_SCOPE_AGENT);
        }
        uint32_t* peer = flags + (size_t)(bg * 16 + tid) * FLAGSTRIDE;
        while (__hip_atomic_load(peer, __ATOMIC_RELAXED,
                                 __HIP_MEMORY_SCOPE_AGENT) < (uint32_t)(t + 1)) {
        }
      }
      __syncthreads();
    }
  }
}

extern "C" void kernel_launch(void* const* d_in, const int* in_sizes, int n_in,
                              void* d_out, int out_size, void* d_ws, size_t ws_size,
                              hipStream_t stream) {
  (void)in_sizes; (void)n_in; (void)out_size; (void)ws_size;
  const int*   x     = (const int*)d_in[0];
  const float* h0    = (const float*)d_in[1];
  const float* c0    = (const float*)d_in[2];
  const float* embed = (const float*)d_in[3];
  const float* w_ih  = (const float*)d_in[4];
  const float* w_hh  = (const float*)d_in[5];
  const float* b_ih  = (const float*)d_in[6];
  const float* b_hh  = (const float*)d_in[7];
  float* out = (float*)d_out;

  char* ws = (char*)d_ws;
  float*    G0p   = (float*)(ws);              // 29*1280*4   = 148480 B
  float*    b1p   = (float*)(ws + 148480);     // 1280*4      =   5120 B
  uint32_t* flags = (uint32_t*)(ws + 153600);  // 4096*4      =  16384 B
  uint16_t* Hx0   = (uint16_t*)(ws + 169984);  // 2*512*320*2 = 655360 B
  uint16_t* Hx1   = (uint16_t*)(ws + 825344);  // 2*512*320*2 = 655360 B

  hipLaunchKernelGGL(prep_kernel, dim3(326), dim3(256), 0, stream,
                     embed, w_ih, b_ih, b_hh, h0, G0p, b1p, flags, Hx0, Hx1);

  void* args[] = { (void*)&x, (void*)&c0, (void*)&w_ih, (void*)&w_hh,
                   (void*)&G0p, (void*)&b1p, (void*)&Hx0, (void*)&Hx1,
                   (void*)&flags, (void*)&out };
  hipLaunchCooperativeKernel((const void*)rnnt_kernel, dim3(256), dim3(320),
                             args, 0, stream);
}